// Round 5
// baseline (433.542 us; speedup 1.0000x reference)
//
#include <hip/hip_runtime.h>

// LSTM B=4096 T=512 IN=14 H=28 OUT=2, fp32 in/out.
// R5: fully wave-private recurrence. One 64-lane wave owns WB=4 batches and
// computes ALL 112 gate-outputs itself: 7 N-tiles x 2 K-tiles = 14
// mfma_f32_16x16x32_bf16 per step (A rows 0..3 = batches, rows 4..15 dup;
// B = [W_hh | W_ih] fragments resident in VGPRs, bias preloaded as C-init).
// Gate->element regroup and h recycle go through wave-private LDS; the only
// barriers are single-wave __syncthreads (≈ waitcnt, no inter-wave wait).
// Grid = 1024 single-wave blocks -> 1 independent chain per SIMD, all SIMDs.

#define T_STEPS 512
#define BATCH   4096
#define IN_F    14
#define HID     28
#define OUT_N   2
#define WB      4                  // batches per wave
#define TC      32                 // timesteps per x chunk
#define NCHUNK  (T_STEPS / TC)     // 16
#define NT      7                  // N-tiles: 112 gate-outputs / 16
#define XREGS   ((WB * TC * IN_F) / 64)   // 28 staging values per lane

typedef __attribute__((ext_vector_type(8))) short  short8;
typedef __attribute__((ext_vector_type(4))) float  float4v;

#define L1 1.4426950408889634f
#define L2 2.8853900817779268f

__device__ __forceinline__ unsigned short f2bf(float f) {
    union { float f; unsigned int u; } v; v.f = f;
    unsigned int r = (v.u + 0x7FFFu + ((v.u >> 16) & 1u)) >> 16;  // RNE
    return (unsigned short)r;
}

__global__ __launch_bounds__(64, 1)
void lstm_wave(const float* __restrict__ x,
               const float* __restrict__ W_ih,
               const float* __restrict__ W_hh,
               const float* __restrict__ b_ih,
               const float* __restrict__ b_hh,
               const float* __restrict__ W_out,
               const float* __restrict__ b_out,
               float* __restrict__ out) {
    __shared__ __align__(16) short h_a[WB][32];          // bf16 h rows, cols 0..27 (28..31 = 0)
    __shared__ __align__(16) short x_a[TC][WB][32];      // bf16 x rows, cols 0..13 (14..31 = 0)
    __shared__ __align__(16) float pre[4 * HID * WB];    // preacts [n][b], n = g*28+u
    __shared__ float hfin[HID * WB];                     // final h, [u][b]

    const int l  = threadIdx.x;      // 0..63
    const int q  = l >> 4;
    const int m  = l & 15;
    const int mb = m & (WB - 1);     // A-row batch (rows 4..15 duplicate 0..3)
    const int b0 = blockIdx.x * WB;

    // ---- weights -> VGPR B-fragments; bias as resident C-init vectors ----
    // B[k][n]: lane l=q*16+m holds k=q*8+j, n=nt*16+m (n in [0,112) always valid)
    short8  bfrag[2][NT];            // [ktile][ntile]
    float4v biasv[NT];
    #pragma unroll
    for (int nt = 0; nt < NT; ++nt) {
        const int n = nt * 16 + m;
        const float bsum = b_ih[n] + b_hh[n];
        biasv[nt] = (float4v){bsum, bsum, bsum, bsum};
        #pragma unroll
        for (int kt = 0; kt < 2; ++kt) {
            short8 v;
            #pragma unroll
            for (int j = 0; j < 8; ++j) {
                const int k = q * 8 + j;
                float w = 0.0f;
                if (kt == 0) { if (k < HID)  w = W_hh[n * HID + k]; }
                else         { if (k < IN_F) w = W_ih[n * IN_F + k]; }
                v[j] = (short)f2bf(w);
            }
            bfrag[kt][nt] = v;
        }
    }

    // ---- zero LDS: h0 = 0 (incl pads), x pads = 0 (cols 14..31 stay 0) ----
    #pragma unroll
    for (int u = l; u < (WB * 32) / 2; u += 64) ((int*)h_a)[u] = 0;
    for (int u = l; u < (TC * WB * 32) / 2; u += 64) ((int*)x_a)[u] = 0;
    __syncthreads();

    // combine-phase element ownership: e = l (p0) and e = 64+l for l<48 (p1);
    // e -> (b = e&3, u = e>>2)
    const int cb  = l & 3;
    const int u0  = l >> 2;          // 0..15
    const int u1  = 16 + (l >> 2);   // 16..31, valid for l<48 (u1 < 28)
    const bool p1 = (l < 48);
    float c0 = 0.0f, c1 = 0.0f, h0 = 0.0f, h1 = 0.0f;

    for (int ch = 0; ch < NCHUNK; ++ch) {
        // ---- stage x chunk: 28 coalesced global loads -> bf16 A-layout ----
        #pragma unroll
        for (int k = 0; k < XREGS; ++k) {
            const int u  = l + 64 * k;
            const int bb = u / (TC * IN_F);
            const int r  = u - bb * (TC * IN_F);
            const int t  = r / IN_F;
            const int f  = r - t * IN_F;
            const float xv = x[(long)(b0 + bb) * T_STEPS * IN_F + ch * TC * IN_F + r];
            x_a[t][bb][f] = (short)f2bf(xv);
        }
        __syncthreads();

        for (int tt = 0; tt < TC; ++tt) {
            // ---- MFMA: all 112 gate preacts for 4 batches ----
            short8 ah = *(const short8*)&h_a[mb][q * 8];
            short8 ax = *(const short8*)&x_a[tt][mb][q * 8];
            float4v acc[NT];
            #pragma unroll
            for (int nt = 0; nt < NT; ++nt)
                acc[nt] = __builtin_amdgcn_mfma_f32_16x16x32_bf16(ah, bfrag[0][nt], biasv[nt], 0, 0, 0);
            #pragma unroll
            for (int nt = 0; nt < NT; ++nt)
                acc[nt] = __builtin_amdgcn_mfma_f32_16x16x32_bf16(ax, bfrag[1][nt], acc[nt], 0, 0, 0);
            // C/D: col = m (n), row = q*4+r (batch); rows 0..3 live in q==0 lanes
            if (q == 0) {
                #pragma unroll
                for (int nt = 0; nt < NT; ++nt)
                    *(float4v*)&pre[(nt * 16 + m) * WB] = acc[nt];
            }
            __syncthreads();   // wave-local: preacts visible

            // ---- combine: merged-rcp gates, c in registers ----
            {
                float pi = pre[(0 * HID + u0) * WB + cb];
                float pf = pre[(1 * HID + u0) * WB + cb];
                float pg = pre[(2 * HID + u0) * WB + cb];
                float po = pre[(3 * HID + u0) * WB + cb];
                float ei = __builtin_amdgcn_exp2f(pi * (-L1));
                float ef = __builtin_amdgcn_exp2f(pf * (-L1));
                float eg = __builtin_amdgcn_exp2f(pg * (-L2));
                float eo = __builtin_amdgcn_exp2f(po * (-L1));
                float av = 1.0f + ei, bv = 1.0f + ef, dv = 1.0f + eg, vv = 1.0f + eo;
                float pd  = av * dv;
                float rv  = __builtin_amdgcn_rcpf(pd * bv);
                float sfv = pd * rv;                       // sigma(f)
                float igv = (1.0f - eg) * bv * rv;         // sigma(i)*tanh(g)
                c0 = fmaf(sfv, c0, igv);
                float ec = __builtin_amdgcn_exp2f(c0 * (-L2));
                float wv = 1.0f + ec;
                float r2 = __builtin_amdgcn_rcpf(vv * wv);
                h0 = (1.0f - ec) * r2;                     // sigma(o)*tanh(c)
                h_a[cb][u0] = (short)f2bf(h0);
            }
            if (p1) {
                float pi = pre[(0 * HID + u1) * WB + cb];
                float pf = pre[(1 * HID + u1) * WB + cb];
                float pg = pre[(2 * HID + u1) * WB + cb];
                float po = pre[(3 * HID + u1) * WB + cb];
                float ei = __builtin_amdgcn_exp2f(pi * (-L1));
                float ef = __builtin_amdgcn_exp2f(pf * (-L1));
                float eg = __builtin_amdgcn_exp2f(pg * (-L2));
                float eo = __builtin_amdgcn_exp2f(po * (-L1));
                float av = 1.0f + ei, bv = 1.0f + ef, dv = 1.0f + eg, vv = 1.0f + eo;
                float pd  = av * dv;
                float rv  = __builtin_amdgcn_rcpf(pd * bv);
                float sfv = pd * rv;
                float igv = (1.0f - eg) * bv * rv;
                c1 = fmaf(sfv, c1, igv);
                float ec = __builtin_amdgcn_exp2f(c1 * (-L2));
                float wv = 1.0f + ec;
                float r2 = __builtin_amdgcn_rcpf(vv * wv);
                h1 = (1.0f - ec) * r2;
                h_a[cb][u1] = (short)f2bf(h1);
            }
            __syncthreads();   // wave-local: h_t visible for next step
        }
    }

    // ---- epilogue: out[b][o] = h_T[b] . W_out[o] + b_out[o] (fp32 h) ----
    hfin[u0 * WB + cb] = h0;
    if (p1) hfin[u1 * WB + cb] = h1;
    __syncthreads();
    if (l < WB * OUT_N) {
        const int o  = l & 1;
        const int bb = l >> 1;
        float s = b_out[o];
        #pragma unroll
        for (int u = 0; u < HID; ++u)
            s = fmaf(hfin[u * WB + bb], W_out[o * HID + u], s);
        out[(b0 + bb) * OUT_N + o] = s;
    }
}

extern "C" void kernel_launch(void* const* d_in, const int* in_sizes, int n_in,
                              void* d_out, int out_size, void* d_ws, size_t ws_size,
                              hipStream_t stream) {
    const float* x     = (const float*)d_in[0];
    const float* W_ih  = (const float*)d_in[1];
    const float* W_hh  = (const float*)d_in[2];
    const float* b_ih  = (const float*)d_in[3];
    const float* b_hh  = (const float*)d_in[4];
    const float* W_out = (const float*)d_in[5];
    const float* b_out = (const float*)d_in[6];
    float* out = (float*)d_out;

    lstm_wave<<<BATCH / WB, 64, 0, stream>>>(
        x, W_ih, W_hh, b_ih, b_hh, W_out, b_out, out);
}